// Round 7
// baseline (110.915 us; speedup 1.0000x reference)
//
#include <hip/hip_runtime.h>
#include <math.h>

#define N_NUC 256
#define N_NB  1024
#define N_ENV 8
#define F0    32
#define F1    16
#define FEAT  256
#define CUTOFF 5.0f

constexpr int NP = N_NUC * N_NB;              // 262144 pairs

typedef float floatx4 __attribute__((ext_vector_type(4)));

__device__ __forceinline__ float rlf(float x, int i) {
    // v_readlane_b32: i is wave-uniform (SGPR or literal); SGPR broadcast result
    return __int_as_float(__builtin_amdgcn_readlane(__float_as_int(x), i));
}

__device__ __forceinline__ void nt_store4(float* p, float4 v) {
    // streaming store: no L2 allocate (global_store_dwordx4 ... nt)
    floatx4 nv = {v.x, v.y, v.z, v.w};
    __builtin_nontemporal_store(nv, reinterpret_cast<floatx4*>(p));
}

// One pair per lane. Block = 256 threads = 4 waves = 256 pairs; 1024 blocks.
// Phase B: 4 pairs per W_gamma LDS pass; outputs via non-temporal stores.
__global__ __launch_bounds__(256, 4) void moon_v6(
    const float* __restrict__ r_nb_ne,   // (256,1024,3)
    const float* __restrict__ R,         // (256,3)
    const float* __restrict__ ne_scales, // (256,8)
    const float* __restrict__ ne_kernel, // (256,4,32)
    const float* __restrict__ ne_bias,   // (256,32)
    const float* __restrict__ env_weight,// (8,32)
    const float* __restrict__ W_beta,    // (32,16)
    const float* __restrict__ W_gamma,   // (16,256)
    const float* __restrict__ W_edge,    // (4,256)
    const float* __restrict__ b_edge,    // (256)
    const float* __restrict__ z_n,       // (256,256)
    float* __restrict__ out)
{
    __shared__ float wgS[F1][FEAT];      // 16 KB: W_gamma
    __shared__ float aS[F0][16];         // 2 KB: per-k {K0,K1,K2,K3,bias,ew0..7,pad3}
    __shared__ float wbS[F0][F1];        // 2 KB: W_beta

    const int tid  = threadIdx.x;
    const int lane = tid & 63;
    const int wid  = tid >> 6;
    const int n    = blockIdx.x >> 2;                    // 4 blocks per nucleus
    const int e0   = (blockIdx.x & 3) * 256 + wid * 64;  // wave's electron base
    const int pair0 = n * N_NB + e0;                     // wave's pairs: pair0 + [0,64)

    // ---- stage LDS ----
    {
        const float4* src = reinterpret_cast<const float4*>(W_gamma);
        float4* dst = reinterpret_cast<float4*>(&wgS[0][0]);
        #pragma unroll
        for (int i = 0; i < 4; ++i) dst[tid + i * 256] = src[tid + i * 256];
    }
    if (tid < F0) {
        const int k = tid;
        aS[k][0] = ne_kernel[n * 128 + 0 * 32 + k];
        aS[k][1] = ne_kernel[n * 128 + 1 * 32 + k];
        aS[k][2] = ne_kernel[n * 128 + 2 * 32 + k];
        aS[k][3] = ne_kernel[n * 128 + 3 * 32 + k];
        aS[k][4] = ne_bias[n * 32 + k];
        #pragma unroll
        for (int v = 0; v < N_ENV; ++v) aS[k][5 + v] = env_weight[v * 32 + k];
        aS[k][13] = 0.f; aS[k][14] = 0.f; aS[k][15] = 0.f;
        #pragma unroll
        for (int j = 0; j < F1; ++j) wbS[k][j] = W_beta[k * F1 + j];
    }

    // ---- per-lane FEAT-slice weights (registers) ----
    const int f0 = lane * 4;
    float4 we4[4];
    #pragma unroll
    for (int c = 0; c < 4; ++c)
        we4[c] = *reinterpret_cast<const float4*>(&W_edge[c * FEAT + f0]);
    float4 zb4 = *reinterpret_cast<const float4*>(&z_n[n * FEAT + f0]);
    {
        float4 b4 = *reinterpret_cast<const float4*>(&b_edge[f0]);
        zb4.x += b4.x; zb4.y += b4.y; zb4.z += b4.z; zb4.w += b4.w;
    }

    // ---- own pair: geometry, envelope basis, cut, inp ----
    const float Rx = R[n * 3 + 0], Ry = R[n * 3 + 1], Rz = R[n * 3 + 2];
    const size_t pr = (size_t)(pair0 + lane) * 3;
    const float dx = r_nb_ne[pr + 0] - Rx;
    const float dy = r_nb_ne[pr + 1] - Ry;
    const float dz = r_nb_ne[pr + 2] - Rz;
    const float d  = sqrtf(dx * dx + dy * dy + dz * dz);

    float E[N_ENV];
    #pragma unroll
    for (int v = 0; v < N_ENV; ++v) E[v] = __expf(-d * ne_scales[n * N_ENV + v]);

    const float xcv = d * (1.0f / CUTOFF);
    const float om  = 1.0f - xcv;
    const float cut = (xcv < 1.0f) ? om * om * (1.0f + 2.0f * xcv) : 0.0f;
    const float i0v = log1pf(d);
    const float li  = __fdividef(i0v, d);
    const float i1v = dx * li, i2v = dy * li, i3v = dz * li;

    __syncthreads();  // LDS ready

    // ---- Phase A: per-lane beta[16] over k (all weight operands LDS-broadcast) ----
    float b[F1];
    #pragma unroll
    for (int j = 0; j < F1; ++j) b[j] = 0.f;

    for (int k = 0; k < F0; ++k) {
        const float4 a0 = *reinterpret_cast<const float4*>(&aS[k][0]);
        const float4 a1 = *reinterpret_cast<const float4*>(&aS[k][4]);
        const float4 a2 = *reinterpret_cast<const float4*>(&aS[k][8]);
        const float ew7 = aS[k][12];
        const float4 w0 = *reinterpret_cast<const float4*>(&wbS[k][0]);
        const float4 w1 = *reinterpret_cast<const float4*>(&wbS[k][4]);
        const float4 w2 = *reinterpret_cast<const float4*>(&wbS[k][8]);
        const float4 w3 = *reinterpret_cast<const float4*>(&wbS[k][12]);
        const float pre = d * a0.x + dx * a0.y + dy * a0.z + dz * a0.w + a1.x;
        float env = E[0] * a1.y + E[1] * a1.z + E[2] * a1.w;
        env += E[3] * a2.x + E[4] * a2.y + E[5] * a2.z + E[6] * a2.w;
        env += E[7] * ew7;
        const float ex = __expf(2.f * pre);
        const float th = 1.f - __fdividef(2.f, ex + 1.f);
        const float h  = th * env;
        b[0]  += h * w0.x;  b[1]  += h * w0.y;  b[2]  += h * w0.z;  b[3]  += h * w0.w;
        b[4]  += h * w1.x;  b[5]  += h * w1.y;  b[6]  += h * w1.z;  b[7]  += h * w1.w;
        b[8]  += h * w2.x;  b[9]  += h * w2.y;  b[10] += h * w2.z;  b[11] += h * w2.w;
        b[12] += h * w3.x;  b[13] += h * w3.y;  b[14] += h * w3.z;  b[15] += h * w3.w;
    }
    #pragma unroll
    for (int j = 0; j < F1; ++j) b[j] *= cut;

    // ---- Phase B: 16 groups x 4 pairs; one W_gamma LDS pass per group ----
    float* __restrict__ gamma_out = out;
    float* __restrict__ edge_out  = out + (size_t)NP * FEAT;

    for (int grp = 0; grp < 16; ++grp) {
        const int p0 = grp * 4;                  // wave-uniform
        float4 g0 = {0,0,0,0}, g1 = {0,0,0,0}, g2 = {0,0,0,0}, g3 = {0,0,0,0};
        #pragma unroll
        for (int j = 0; j < F1; ++j) {
            const float4 wg = *reinterpret_cast<const float4*>(&wgS[j][f0]);
            const float bj0 = rlf(b[j], p0 + 0);
            const float bj1 = rlf(b[j], p0 + 1);
            const float bj2 = rlf(b[j], p0 + 2);
            const float bj3 = rlf(b[j], p0 + 3);
            g0.x += bj0 * wg.x; g0.y += bj0 * wg.y; g0.z += bj0 * wg.z; g0.w += bj0 * wg.w;
            g1.x += bj1 * wg.x; g1.y += bj1 * wg.y; g1.z += bj1 * wg.z; g1.w += bj1 * wg.w;
            g2.x += bj2 * wg.x; g2.y += bj2 * wg.y; g2.z += bj2 * wg.z; g2.w += bj2 * wg.w;
            g3.x += bj3 * wg.x; g3.y += bj3 * wg.y; g3.z += bj3 * wg.z; g3.w += bj3 * wg.w;
        }
        #pragma unroll
        for (int q = 0; q < 4; ++q) {
            const int p = p0 + q;
            const float e0s = rlf(i0v, p), e1s = rlf(i1v, p);
            const float e2s = rlf(i2v, p), e3s = rlf(i3v, p);
            float4 ed;
            ed.x = e0s * we4[0].x + e1s * we4[1].x + e2s * we4[2].x + e3s * we4[3].x + zb4.x;
            ed.y = e0s * we4[0].y + e1s * we4[1].y + e2s * we4[2].y + e3s * we4[3].y + zb4.y;
            ed.z = e0s * we4[0].z + e1s * we4[1].z + e2s * we4[2].z + e3s * we4[3].z + zb4.z;
            ed.w = e0s * we4[0].w + e1s * we4[1].w + e2s * we4[2].w + e3s * we4[3].w + zb4.w;
            const float4 gq = (q == 0) ? g0 : (q == 1) ? g1 : (q == 2) ? g2 : g3;
            const size_t base = (size_t)(pair0 + p) * FEAT + f0;
            nt_store4(&gamma_out[base], gq);
            nt_store4(&edge_out[base], ed);
        }
    }
}

extern "C" void kernel_launch(void* const* d_in, const int* in_sizes, int n_in,
                              void* d_out, int out_size, void* d_ws, size_t ws_size,
                              hipStream_t stream) {
    const float* r_nb_ne    = (const float*)d_in[0];
    const float* R          = (const float*)d_in[1];
    const float* ne_scales  = (const float*)d_in[2];
    const float* ne_kernel  = (const float*)d_in[3];
    const float* ne_bias    = (const float*)d_in[4];
    const float* env_weight = (const float*)d_in[5];
    const float* W_beta     = (const float*)d_in[6];
    const float* W_gamma    = (const float*)d_in[7];
    const float* W_edge     = (const float*)d_in[8];
    const float* b_edge     = (const float*)d_in[9];
    const float* z_n        = (const float*)d_in[10];
    float* out = (float*)d_out;

    moon_v6<<<NP / 256, 256, 0, stream>>>(
        r_nb_ne, R, ne_scales, ne_kernel, ne_bias, env_weight,
        W_beta, W_gamma, W_edge, b_edge, z_n, out);
}

// Round 8
// 106.284 us; speedup vs baseline: 1.0436x; 1.0436x over previous
//
#include <hip/hip_runtime.h>
#include <math.h>

#define N_NUC 256
#define N_NB  1024
#define N_ENV 8
#define F0    32
#define F1    16
#define FEAT  256
#define CUTOFF 5.0f

constexpr int NP = N_NUC * N_NB;              // 262144 pairs
constexpr int GBLOCKS = NP / 256;             // 1024 gamma blocks
constexpr int EBLOCKS = NP / 256;             // 1024 edge blocks

__device__ __forceinline__ float rlf(float x, int i) {
    // v_readlane_b32: i is wave-uniform (SGPR or literal); SGPR broadcast result
    return __int_as_float(__builtin_amdgcn_readlane(__float_as_int(x), i));
}

// Split grid: blocks [0,1024) write gamma only (full filter pipeline);
// blocks [1024,2048) write edge only (near-pure streaming, starts immediately).
__global__ __launch_bounds__(256) void moon_v8(
    const float* __restrict__ r_nb_ne,   // (256,1024,3)
    const float* __restrict__ R,         // (256,3)
    const float* __restrict__ ne_scales, // (256,8)
    const float* __restrict__ ne_kernel, // (256,4,32)
    const float* __restrict__ ne_bias,   // (256,32)
    const float* __restrict__ env_weight,// (8,32)
    const float* __restrict__ W_beta,    // (32,16)
    const float* __restrict__ W_gamma,   // (16,256)
    const float* __restrict__ W_edge,    // (4,256)
    const float* __restrict__ b_edge,    // (256)
    const float* __restrict__ z_n,       // (256,256)
    float* __restrict__ out)
{
    __shared__ float wgS[F1][FEAT];      // 16 KB (gamma blocks only)
    __shared__ float aS[F0][16];         // 2 KB
    __shared__ float wbS[F0][F1];        // 2 KB

    const int tid  = threadIdx.x;
    const int lane = tid & 63;
    const int wid  = tid >> 6;

    if (blockIdx.x >= GBLOCKS) {
        // ================= EDGE half: near-pure streaming =================
        const int b    = blockIdx.x - GBLOCKS;
        const int n    = b >> 2;
        const int e0   = (b & 3) * 256 + wid * 64;
        const int pair0 = n * N_NB + e0;
        const int f0   = lane * 4;

        float4 we4[4];
        #pragma unroll
        for (int c = 0; c < 4; ++c)
            we4[c] = *reinterpret_cast<const float4*>(&W_edge[c * FEAT + f0]);
        float4 zb4 = *reinterpret_cast<const float4*>(&z_n[n * FEAT + f0]);
        {
            float4 b4 = *reinterpret_cast<const float4*>(&b_edge[f0]);
            zb4.x += b4.x; zb4.y += b4.y; zb4.z += b4.z; zb4.w += b4.w;
        }

        const float Rx = R[n * 3 + 0], Ry = R[n * 3 + 1], Rz = R[n * 3 + 2];
        const size_t pr = (size_t)(pair0 + lane) * 3;
        const float dx = r_nb_ne[pr + 0] - Rx;
        const float dy = r_nb_ne[pr + 1] - Ry;
        const float dz = r_nb_ne[pr + 2] - Rz;
        const float d  = sqrtf(dx * dx + dy * dy + dz * dz);
        const float i0v = log1pf(d);
        const float li  = __fdividef(i0v, d);
        const float i1v = dx * li, i2v = dy * li, i3v = dz * li;

        float* __restrict__ edge_out = out + (size_t)NP * FEAT;

        for (int p = 0; p < 64; ++p) {
            const float e0s = rlf(i0v, p), e1s = rlf(i1v, p);
            const float e2s = rlf(i2v, p), e3s = rlf(i3v, p);
            float4 ed;
            ed.x = e0s * we4[0].x + e1s * we4[1].x + e2s * we4[2].x + e3s * we4[3].x + zb4.x;
            ed.y = e0s * we4[0].y + e1s * we4[1].y + e2s * we4[2].y + e3s * we4[3].y + zb4.y;
            ed.z = e0s * we4[0].z + e1s * we4[1].z + e2s * we4[2].z + e3s * we4[3].z + zb4.z;
            ed.w = e0s * we4[0].w + e1s * we4[1].w + e2s * we4[2].w + e3s * we4[3].w + zb4.w;
            const size_t base = (size_t)(pair0 + p) * FEAT + f0;
            *reinterpret_cast<float4*>(&edge_out[base]) = ed;
        }
        return;
    }

    // ================= GAMMA half: full filter pipeline =================
    const int n    = blockIdx.x >> 2;
    const int e0   = (blockIdx.x & 3) * 256 + wid * 64;
    const int pair0 = n * N_NB + e0;

    // ---- stage LDS ----
    {
        const float4* src = reinterpret_cast<const float4*>(W_gamma);
        float4* dst = reinterpret_cast<float4*>(&wgS[0][0]);
        #pragma unroll
        for (int i = 0; i < 4; ++i) dst[tid + i * 256] = src[tid + i * 256];
    }
    if (tid < F0) {
        const int k = tid;
        aS[k][0] = ne_kernel[n * 128 + 0 * 32 + k];
        aS[k][1] = ne_kernel[n * 128 + 1 * 32 + k];
        aS[k][2] = ne_kernel[n * 128 + 2 * 32 + k];
        aS[k][3] = ne_kernel[n * 128 + 3 * 32 + k];
        aS[k][4] = ne_bias[n * 32 + k];
        #pragma unroll
        for (int v = 0; v < N_ENV; ++v) aS[k][5 + v] = env_weight[v * 32 + k];
        aS[k][13] = 0.f; aS[k][14] = 0.f; aS[k][15] = 0.f;
        #pragma unroll
        for (int j = 0; j < F1; ++j) wbS[k][j] = W_beta[k * F1 + j];
    }

    // ---- own pair: geometry, envelope basis, cut ----
    const float Rx = R[n * 3 + 0], Ry = R[n * 3 + 1], Rz = R[n * 3 + 2];
    const size_t pr = (size_t)(pair0 + lane) * 3;
    const float dx = r_nb_ne[pr + 0] - Rx;
    const float dy = r_nb_ne[pr + 1] - Ry;
    const float dz = r_nb_ne[pr + 2] - Rz;
    const float d  = sqrtf(dx * dx + dy * dy + dz * dz);

    float E[N_ENV];
    #pragma unroll
    for (int v = 0; v < N_ENV; ++v) E[v] = __expf(-d * ne_scales[n * N_ENV + v]);

    const float xcv = d * (1.0f / CUTOFF);
    const float om  = 1.0f - xcv;
    const float cut = (xcv < 1.0f) ? om * om * (1.0f + 2.0f * xcv) : 0.0f;

    __syncthreads();  // LDS ready

    // ---- Phase A: per-lane beta[16] over k ----
    float b[F1];
    #pragma unroll
    for (int j = 0; j < F1; ++j) b[j] = 0.f;

    for (int k = 0; k < F0; ++k) {
        const float4 a0 = *reinterpret_cast<const float4*>(&aS[k][0]);
        const float4 a1 = *reinterpret_cast<const float4*>(&aS[k][4]);
        const float4 a2 = *reinterpret_cast<const float4*>(&aS[k][8]);
        const float ew7 = aS[k][12];
        const float4 w0 = *reinterpret_cast<const float4*>(&wbS[k][0]);
        const float4 w1 = *reinterpret_cast<const float4*>(&wbS[k][4]);
        const float4 w2 = *reinterpret_cast<const float4*>(&wbS[k][8]);
        const float4 w3 = *reinterpret_cast<const float4*>(&wbS[k][12]);
        const float pre = d * a0.x + dx * a0.y + dy * a0.z + dz * a0.w + a1.x;
        float env = E[0] * a1.y + E[1] * a1.z + E[2] * a1.w;
        env += E[3] * a2.x + E[4] * a2.y + E[5] * a2.z + E[6] * a2.w;
        env += E[7] * ew7;
        const float ex = __expf(2.f * pre);
        const float th = 1.f - __fdividef(2.f, ex + 1.f);
        const float h  = th * env;
        b[0]  += h * w0.x;  b[1]  += h * w0.y;  b[2]  += h * w0.z;  b[3]  += h * w0.w;
        b[4]  += h * w1.x;  b[5]  += h * w1.y;  b[6]  += h * w1.z;  b[7]  += h * w1.w;
        b[8]  += h * w2.x;  b[9]  += h * w2.y;  b[10] += h * w2.z;  b[11] += h * w2.w;
        b[12] += h * w3.x;  b[13] += h * w3.y;  b[14] += h * w3.z;  b[15] += h * w3.w;
    }
    #pragma unroll
    for (int j = 0; j < F1; ++j) b[j] *= cut;

    // ---- Phase B: 16 groups x 4 pairs; one W_gamma LDS pass per group ----
    const int f0 = lane * 4;
    float* __restrict__ gamma_out = out;

    for (int grp = 0; grp < 16; ++grp) {
        const int p0 = grp * 4;                  // wave-uniform
        float4 g0 = {0,0,0,0}, g1 = {0,0,0,0}, g2 = {0,0,0,0}, g3 = {0,0,0,0};
        #pragma unroll
        for (int j = 0; j < F1; ++j) {
            const float4 wg = *reinterpret_cast<const float4*>(&wgS[j][f0]);
            const float bj0 = rlf(b[j], p0 + 0);
            const float bj1 = rlf(b[j], p0 + 1);
            const float bj2 = rlf(b[j], p0 + 2);
            const float bj3 = rlf(b[j], p0 + 3);
            g0.x += bj0 * wg.x; g0.y += bj0 * wg.y; g0.z += bj0 * wg.z; g0.w += bj0 * wg.w;
            g1.x += bj1 * wg.x; g1.y += bj1 * wg.y; g1.z += bj1 * wg.z; g1.w += bj1 * wg.w;
            g2.x += bj2 * wg.x; g2.y += bj2 * wg.y; g2.z += bj2 * wg.z; g2.w += bj2 * wg.w;
            g3.x += bj3 * wg.x; g3.y += bj3 * wg.y; g3.z += bj3 * wg.z; g3.w += bj3 * wg.w;
        }
        #pragma unroll
        for (int q = 0; q < 4; ++q) {
            const int p = p0 + q;
            const float4 gq = (q == 0) ? g0 : (q == 1) ? g1 : (q == 2) ? g2 : g3;
            const size_t base = (size_t)(pair0 + p) * FEAT + f0;
            *reinterpret_cast<float4*>(&gamma_out[base]) = gq;
        }
    }
}

extern "C" void kernel_launch(void* const* d_in, const int* in_sizes, int n_in,
                              void* d_out, int out_size, void* d_ws, size_t ws_size,
                              hipStream_t stream) {
    const float* r_nb_ne    = (const float*)d_in[0];
    const float* R          = (const float*)d_in[1];
    const float* ne_scales  = (const float*)d_in[2];
    const float* ne_kernel  = (const float*)d_in[3];
    const float* ne_bias    = (const float*)d_in[4];
    const float* env_weight = (const float*)d_in[5];
    const float* W_beta     = (const float*)d_in[6];
    const float* W_gamma    = (const float*)d_in[7];
    const float* W_edge     = (const float*)d_in[8];
    const float* b_edge     = (const float*)d_in[9];
    const float* z_n        = (const float*)d_in[10];
    float* out = (float*)d_out;

    moon_v8<<<GBLOCKS + EBLOCKS, 256, 0, stream>>>(
        r_nb_ne, R, ne_scales, ne_kernel, ne_bias, env_weight,
        W_beta, W_gamma, W_edge, b_edge, z_n, out);
}